// Round 3
// baseline (75.745 us; speedup 1.0000x reference)
//
#include <hip/hip_runtime.h>
#include <cstdint>

// YOLO loss. B=32, H=W=32, A=9, C=80, T=50, NET=512.
// Block = 256 threads = 64 cells. Each wave DMAs its own 5440-B slice of
// y_pred/y_true into LDS via global_load_lds(width=16), then 4 lanes
// cooperate per cell reading from LDS. Grid = 4608 blocks.

constexpr int NT   = 50;
constexpr int SPAN = 64 * 85;   // 5440 floats per array per block

#define G2L(gp, lp) __builtin_amdgcn_global_load_lds(                      \
    (const __attribute__((address_space(1))) void*)(gp),                   \
    (__attribute__((address_space(3))) void*)(lp), 16, 0, 0)

__global__ __launch_bounds__(256) void yolo_loss_kernel(
    const float* __restrict__ y_pred,     // (B,H,W,A,85) flat
    const float* __restrict__ y_true,     // (B,H,W,A,85)
    const float* __restrict__ true_boxes, // (B,50,4)
    const float* __restrict__ anchors,    // (9,2)
    float* __restrict__ out)              // (B,)
{
    __shared__ float s_pred[SPAN];
    __shared__ float s_true[SPAN];
    __shared__ float s_tminx[NT], s_tminy[NT], s_tmaxx[NT], s_tmaxy[NT], s_tarea[NT];
    __shared__ float s_anch[18];
    __shared__ float s_red[4];

    const int tid  = threadIdx.x;
    const int lane = tid & 63;
    const int wid  = tid >> 6;

    const int cell0 = blockIdx.x * 64;       // all 64 cells share batch b
    const int b     = cell0 / 9216;

    // ---- direct global->LDS DMA: wave wid copies its own 1360-float slice
    //      of each array. 5440 B = 5*1024 + 320. LDS dest is wave-uniform;
    //      HW adds lane*16. ----
    {
        const size_t gbase = (size_t)cell0 * 85 + (size_t)wid * 1360 + (size_t)lane * 4;
        const float* gp = y_pred + gbase;
        const float* gt = y_true + gbase;
        float* lp = s_pred + wid * 1360;     // wave-uniform
        float* lt = s_true + wid * 1360;
        #pragma unroll
        for (int k = 0; k < 5; ++k) {
            G2L(gp + k * 256, lp + k * 256);
            G2L(gt + k * 256, lt + k * 256);
        }
        if (lane < 20) {                     // 320-B tail
            G2L(gp + 5 * 256, lp + 5 * 256);
            G2L(gt + 5 * 256, lt + 5 * 256);
        }
    }

    // ---- small tables (overlap with DMA) ----
    if (tid < NT) {
        const float* tb = true_boxes + ((size_t)b * NT + tid) * 4;
        float tx = tb[0] * (1.0f / 32.0f);
        float ty = tb[1] * (1.0f / 32.0f);
        float tw = tb[2] * (1.0f / 512.0f);
        float th = tb[3] * (1.0f / 512.0f);
        s_tminx[tid] = tx - tw * 0.5f;
        s_tmaxx[tid] = tx + tw * 0.5f;
        s_tminy[tid] = ty - th * 0.5f;
        s_tmaxy[tid] = ty + th * 0.5f;
        s_tarea[tid] = tw * th;
    }
    if (tid < 18) s_anch[tid] = anchors[tid];
    __syncthreads();                          // drains vmcnt (DMA) + lgkmcnt

    const int s = tid & 3;                    // slice within cell group
    const int g = tid >> 2;                   // cell within block: 0..63

    const int cell  = cell0 + g;
    const int local = cell - b * 9216;
    const int a = local % 9;
    const int w = (local / 9) % 32;
    const int h = local / 288;

    const float* cp = s_pred + g * 85;
    const float* ct = s_true + g * 85;

    // box fields: direct LDS reads (4 lanes of a group broadcast-read same addr)
    const float p0 = cp[0], p1 = cp[1], p2 = cp[2], p3 = cp[3], p4 = cp[4];
    const float t0 = ct[0], t1 = ct[1], t2 = ct[2], t3 = ct[3], t4 = ct[4];

    const float aw = s_anch[a * 2 + 0];
    const float ah = s_anch[a * 2 + 1];

    const float sig0  = 1.0f / (1.0f + __expf(-p0));
    const float sig1  = 1.0f / (1.0f + __expf(-p1));
    const float predx = (float)w + sig0;
    const float predy = (float)h + sig1;
    const float pconf = 1.0f / (1.0f + __expf(-p4));

    const float px = predx * (1.0f / 32.0f);
    const float py = predy * (1.0f / 32.0f);
    const float pw = __expf(p2) * aw * (1.0f / 512.0f);
    const float ph = __expf(p3) * ah * (1.0f / 512.0f);
    const float pminx = px - pw * 0.5f, pmaxx = px + pw * 0.5f;
    const float pminy = py - ph * 0.5f, pmaxy = py + ph * 0.5f;
    const float parea = pw * ph;

    // ---- IoU ignore flag, 12-13 boxes per lane; OR-combine across group ----
    int ig = 0;
    #pragma unroll
    for (int i = 0; i < 13; ++i) {
        const int box = i * 4 + s;
        if (box < NT) {
            float iw = fminf(pmaxx, s_tmaxx[box]) - fmaxf(pminx, s_tminx[box]);
            float ih = fminf(pmaxy, s_tmaxy[box]) - fmaxf(pminy, s_tminy[box]);
            iw = fmaxf(iw, 0.0f);
            ih = fmaxf(ih, 0.0f);
            float inter = iw * ih;
            float uni   = parea + s_tarea[box] - inter;
            ig |= (2.0f * inter >= uni) ? 1 : 0;
        }
    }
    ig |= __shfl_xor(ig, 1);
    ig |= __shfl_xor(ig, 2);

    // ---- classes: lane s owns floats f = 4j+s (classes are f>=5).
    //      Pass A: load pred to regs, argmax(true) online, max(pred).
    //      Pass B: sum exp(pred - max), 4 accumulators. ----
    float pv[21];
    float tmax = -1e30f, p_at = 0.0f, pmax = -1e30f;
    #pragma unroll
    for (int j = 0; j < 21; ++j) {
        const int f = 4 * j + s;
        const float pc = cp[f];
        const float tc = ct[f];
        pv[j] = pc;
        const bool cls = (f >= 5);            // only j==0 (all s) and j==1 (s==0) invalid
        const float tcm = cls ? tc : -1e30f;
        if (tcm > tmax) { tmax = tcm; p_at = pc; }
        pmax = fmaxf(pmax, cls ? pc : -1e30f);
    }
    float pv84 = -1e30f, t84m = -1e30f;
    if (s == 0) { pv84 = cp[84]; t84m = ct[84]; }
    if (t84m > tmax) { tmax = t84m; p_at = pv84; }
    pmax = fmaxf(pmax, pv84);

    // combine across the 4 lanes
    #pragma unroll
    for (int d = 1; d <= 2; d <<= 1) {
        const float ot = __shfl_xor(tmax, d);
        const float op = __shfl_xor(p_at, d);
        if (ot > tmax) { tmax = ot; p_at = op; }
        pmax = fmaxf(pmax, __shfl_xor(pmax, d));
    }

    float acc[4] = {0.0f, 0.0f, 0.0f, 0.0f};
    #pragma unroll
    for (int j = 0; j < 21; ++j) {
        const int f = 4 * j + s;
        float e = __expf(pv[j] - pmax);
        if (f < 5) e = 0.0f;
        acc[j & 3] += e;
    }
    if (s == 0) acc[1] += __expf(pv84 - pmax);
    float sum = (acc[0] + acc[1]) + (acc[2] + acc[3]);
    sum += __shfl_xor(sum, 1);
    sum += __shfl_xor(sum, 2);
    const float ce = (pmax + __logf(sum)) - p_at;

    // ---- deltas (lane s==0 emits the cell's partial) ----
    const float om  = t4;
    const float ew  = __expf(t2) * aw * (1.0f / 512.0f);
    const float eh  = __expf(t3) * ah * (1.0f / 512.0f);
    const float whs = 2.0f - ew * eh;

    const float xyd0 = om * (predx - t0) * whs;
    const float xyd1 = om * (predy - t1) * whs;
    const float whd0 = om * (p2 - t2) * whs;
    const float whd1 = om * (p3 - t3) * whs;
    const float cd   = om * (pconf - t4) * 5.0f + (1.0f - om) * (ig ? 0.0f : pconf);

    float partial = xyd0 * xyd0 + xyd1 * xyd1 + whd0 * whd0 + whd1 * whd1 +
                    cd * cd + om * ce;
    partial = (s == 0) ? partial : 0.0f;

    // ---- wave + block reduction, one atomic per block ----
    #pragma unroll
    for (int off = 32; off > 0; off >>= 1)
        partial += __shfl_down(partial, off);

    if (lane == 0) s_red[wid] = partial;
    __syncthreads();
    if (tid == 0)
        atomicAdd(&out[b], s_red[0] + s_red[1] + s_red[2] + s_red[3]);
}

extern "C" void kernel_launch(void* const* d_in, const int* in_sizes, int n_in,
                              void* d_out, int out_size, void* d_ws, size_t ws_size,
                              hipStream_t stream) {
    // setup_inputs order: input_image (unused), y_pred, y_true, true_boxes, anchors
    const float* y_pred     = (const float*)d_in[1];
    const float* y_true     = (const float*)d_in[2];
    const float* true_boxes = (const float*)d_in[3];
    const float* anchors    = (const float*)d_in[4];
    float* out = (float*)d_out;

    hipMemsetAsync(d_out, 0, (size_t)out_size * sizeof(float), stream);

    dim3 grid(294912 / 64);   // 4608 blocks, 64 cells each
    yolo_loss_kernel<<<grid, 256, 0, stream>>>(y_pred, y_true, true_boxes, anchors, out);
}